// Round 10
// baseline (156.144 us; speedup 1.0000x reference)
//
#include <hip/hip_runtime.h>

#define THREADS 256

typedef __attribute__((ext_vector_type(8))) short bf16x8;
typedef __attribute__((ext_vector_type(4))) float f32x4;

// fp32 -> bf16 with round-to-nearest-even (matches HW convert)
__device__ inline unsigned short f2bf(float f) {
    union { float f; unsigned int u; } v; v.f = f;
    unsigned int r = v.u + 0x7fffu + ((v.u >> 16) & 1u);
    return (unsigned short)(r >> 16);
}

// LDS-only barrier: orders LDS producer/consumer WITHOUT draining vmcnt —
// global stores issued before it stay in flight (unlike __syncthreads).
__device__ inline void lds_barrier() {
    asm volatile("s_waitcnt lgkmcnt(0)" ::: "memory");
    __builtin_amdgcn_s_barrier();
    __builtin_amdgcn_sched_barrier(0);
}

// ---------------------------------------------------------------------------
// Kernel A: in-side contraction  x[N,4096] -> u3b[N,512] (bf16)
//   (EXACT round-0 proven version, ~21 us. FROZEN.)
// ---------------------------------------------------------------------------
__global__ __launch_bounds__(THREADS) void k_in_contract(
    const float* __restrict__ x,
    const float* __restrict__ f3, const float* __restrict__ f4,
    const float* __restrict__ f5,
    unsigned short* __restrict__ u3b, int N)
{
    const int n = blockIdx.x;
    const int t = threadIdx.x;

    __shared__ float fs[256];        // f3 [0..128) | f4 [128..256)
    __shared__ float u1s[256 * 9];   // [de][n6], pad 9 -> 2-way max
    __shared__ float u2s[128 * 9];   // [d*8+m][n6], pad 9

    if (t < 128) { fs[t] = f3[t]; fs[128 + t] = f4[t]; }

    float xv[16];
    {
        const float4* xr = (const float4*)(x + (size_t)n * 4096 + t * 16);
        float4 a0 = xr[0], a1 = xr[1], a2 = xr[2], a3 = xr[3];
        xv[0]=a0.x; xv[1]=a0.y; xv[2]=a0.z; xv[3]=a0.w;
        xv[4]=a1.x; xv[5]=a1.y; xv[6]=a1.z; xv[7]=a1.w;
        xv[8]=a2.x; xv[9]=a2.y; xv[10]=a2.z; xv[11]=a2.w;
        xv[12]=a3.x; xv[13]=a3.y; xv[14]=a3.z; xv[15]=a3.w;
    }

    float acc8[8];
    #pragma unroll
    for (int q = 0; q < 8; ++q) acc8[q] = 0.f;
    #pragma unroll
    for (int f = 0; f < 16; ++f) {
        const float xf = xv[f];
        #pragma unroll
        for (int n6 = 0; n6 < 8; ++n6)
            acc8[n6] = fmaf(xf, f5[f*8 + n6], acc8[n6]);
    }
    __syncthreads();
    #pragma unroll
    for (int n6 = 0; n6 < 8; ++n6) u1s[t*9 + n6] = acc8[n6];
    __syncthreads();

    {
        const int d = t >> 4, m = (t >> 1) & 7, h = t & 1;
        float fr[16];
        #pragma unroll
        for (int e = 0; e < 16; ++e) fr[e] = fs[128 + e*8 + m];
        float a4[4] = {0.f, 0.f, 0.f, 0.f};
        #pragma unroll
        for (int e = 0; e < 16; ++e) {
            const int base = (d*16 + e)*9 + h*4;
            #pragma unroll
            for (int q = 0; q < 4; ++q)
                a4[q] = fmaf(u1s[base + q], fr[e], a4[q]);
        }
        #pragma unroll
        for (int q = 0; q < 4; ++q) u2s[(d*8 + m)*9 + h*4 + q] = a4[q];
    }
    __syncthreads();

    {
        const int l = t >> 5, m = (t >> 2) & 7, h = t & 3;
        float fr[16];
        #pragma unroll
        for (int d = 0; d < 16; ++d) fr[d] = fs[d*8 + l];
        float a2[2] = {0.f, 0.f};
        #pragma unroll
        for (int d = 0; d < 16; ++d) {
            const int base = (d*8 + m)*9 + h*2;
            a2[0] = fmaf(u2s[base],     fr[d], a2[0]);
            a2[1] = fmaf(u2s[base + 1], fr[d], a2[1]);
        }
        unsigned int pk = (unsigned int)f2bf(a2[0]) |
                          ((unsigned int)f2bf(a2[1]) << 16);
        ((unsigned int*)u3b)[(size_t)n * 256 + t] = pk;
    }
}

// ---------------------------------------------------------------------------
// core fp32 [512,512] -> bf16. (FROZEN)
// ---------------------------------------------------------------------------
__global__ __launch_bounds__(THREADS) void k_convert_core(
    const float* __restrict__ core, unsigned short* __restrict__ coreb)
{
    const int i = blockIdx.x * THREADS + threadIdx.x;
    float4 c = ((const float4*)core)[i];
    ushort4 o;
    o.x = f2bf(c.x); o.y = f2bf(c.y); o.z = f2bf(c.z); o.w = f2bf(c.w);
    ((ushort4*)coreb)[i] = o;
}

// ---------------------------------------------------------------------------
// Kernel B: MFMA GEMM (EXACT round-0 proven version, ~8.6 us. FROZEN.)
//   Wave tile 32x32 (2x2 of 16x16x32 bf16). Grid (32,16) = 512 blocks.
// ---------------------------------------------------------------------------
__global__ __launch_bounds__(THREADS) void k_core_gemm_mfma(
    const unsigned short* __restrict__ u3b,
    const unsigned short* __restrict__ coreb,
    float* __restrict__ v, int N)
{
    const int t    = threadIdx.x;
    const int lane = t & 63;
    const int wave = t >> 6;
    const int m0 = blockIdx.x * 128 + wave * 32;
    const int p0 = blockIdx.y * 32;
    const int lr = lane & 15;
    const int lq = lane >> 4;

    const unsigned short* aptr0 = u3b   + (size_t)(m0 + lr) * 512 + lq * 8;
    const unsigned short* aptr1 = aptr0 + 16 * 512;
    const unsigned short* bptr0 = coreb + (size_t)(p0 + lr) * 512 + lq * 8;
    const unsigned short* bptr1 = bptr0 + 16 * 512;

    f32x4 acc00 = {0.f,0.f,0.f,0.f}, acc01 = {0.f,0.f,0.f,0.f};
    f32x4 acc10 = {0.f,0.f,0.f,0.f}, acc11 = {0.f,0.f,0.f,0.f};

    #pragma unroll
    for (int k0 = 0; k0 < 512; k0 += 32) {
        bf16x8 a0 = *(const bf16x8*)(aptr0 + k0);
        bf16x8 a1 = *(const bf16x8*)(aptr1 + k0);
        bf16x8 b0 = *(const bf16x8*)(bptr0 + k0);
        bf16x8 b1 = *(const bf16x8*)(bptr1 + k0);
        acc00 = __builtin_amdgcn_mfma_f32_16x16x32_bf16(a0, b0, acc00, 0, 0, 0);
        acc01 = __builtin_amdgcn_mfma_f32_16x16x32_bf16(a0, b1, acc01, 0, 0, 0);
        acc10 = __builtin_amdgcn_mfma_f32_16x16x32_bf16(a1, b0, acc10, 0, 0, 0);
        acc11 = __builtin_amdgcn_mfma_f32_16x16x32_bf16(a1, b1, acc11, 0, 0, 0);
    }

    const int row = m0 + lq * 4;
    const int col = p0 + lr;
    #pragma unroll
    for (int r = 0; r < 4; ++r) {
        v[(size_t)(row + r) * 512 + col]           = acc00[r];
        v[(size_t)(row + r) * 512 + col + 16]      = acc01[r];
        v[(size_t)(row + 16 + r) * 512 + col]      = acc10[r];
        v[(size_t)(row + 16 + r) * 512 + col + 16] = acc11[r];
    }
}

// ---------------------------------------------------------------------------
// Kernel C (v7): 4 rows/block, ONE lds_barrier per row, no w2s stage.
//   vs/w1s double-buffered (p = rr&1, full unroll -> static buffer index).
//   y-thread computes its own w2v[k] from w1s: for wave-uniform A = s*4+w,
//   w1[A,j,0..7] = two ds_read_b128 at the SAME address across all 64 lanes
//   -> LDS broadcast, conflict-free. 4x redundant w2 FMAs (~+1us VALU)
//   buy: -1 LDS round-trip and 3->1 barriers per row.
//   Single-barrier proof: barrier(r) separates {y(r-1) reads w1s[p^1],
//   w1(r) reads vs[p], vs[p^1] writes} from {w1(r+1) writes w1s[p^1],
//   y(r) reads w1s[p], vs[p] writes of iter r+1}. Buffers alternate, so
//   every cross-iteration pair is barrier-separated.
//   w1s stride 12 (48B): both-side 16B alignment for b128.
//   Stores: verified coalesced mapping o = s*1024 + t*4 (+q), 1KB/wave.
// ---------------------------------------------------------------------------
__global__ __launch_bounds__(THREADS) void k_out_expand7(
    const float* __restrict__ v,
    const float* __restrict__ f0, const float* __restrict__ f1,
    const float* __restrict__ f2, const float* __restrict__ bias,
    float* __restrict__ y, int N)
{
    const int t  = threadIdx.x;
    const int r0 = blockIdx.x * 4;

    __shared__ float fs[256];           // f0 [0..128) | f1 [128..256)
    __shared__ float vs[2][512];        // double-buffered v row
    __shared__ float w1s[2][128 * 12];  // [a*8+j][k], stride 12 (16B-aligned)

    if (t < 128) { fs[t] = f0[t]; fs[128 + t] = f1[t]; }
    if (t < 128)
        ((float4*)&vs[0][0])[t] = ((const float4*)(v + (size_t)r0 * 512))[t];

    // hoisted per-thread constants (static indices only, rule #20)
    float f2r[32];   // f2 rows c = (t&3)*4 .. +3
    {
        const float4* fp = (const float4*)(f2 + ((t & 3) * 4) * 8);
        #pragma unroll
        for (int q8 = 0; q8 < 8; ++q8) {
            float4 ff = fp[q8];
            f2r[q8*4+0] = ff.x; f2r[q8*4+1] = ff.y;
            f2r[q8*4+2] = ff.z; f2r[q8*4+3] = ff.w;
        }
    }
    const float4* bias4 = (const float4*)bias;
    float4 bb0 = bias4[0*256 + t], bb1 = bias4[1*256 + t];
    float4 bb2 = bias4[2*256 + t], bb3 = bias4[3*256 + t];

    const int a_ = t >> 4, j_ = (t >> 1) & 7, h_ = t & 1;   // w1 roles
    const int w_ = t >> 6, B_ = (t >> 2) & 15;              // y roles

    lds_barrier();   // fs + vs[0] visible

    float fr0[8], fr1[8];
    #pragma unroll
    for (int i = 0; i < 8; ++i) fr0[i] = fs[a_*8 + i];
    #pragma unroll
    for (int j = 0; j < 8; ++j) fr1[j] = fs[128 + B_*8 + j];

    #pragma unroll
    for (int rr = 0; rr < 4; ++rr) {          // full unroll: p static
        const int n = r0 + rr;
        const int p = rr & 1;

        // T14 prefetch: issue next row's v load before compute
        float4 vpf = make_float4(0.f, 0.f, 0.f, 0.f);
        if (rr < 3 && t < 128)
            vpf = ((const float4*)(v + (size_t)(n + 1) * 512))[t];

        // ---- w1 stage: reads vs[p], writes w1s[p] ----
        {
            float a4[4] = {0.f, 0.f, 0.f, 0.f};
            #pragma unroll
            for (int i = 0; i < 8; ++i) {
                const int base = i*64 + j_*8 + h_*4;
                const float fi = fr0[i];
                #pragma unroll
                for (int q = 0; q < 4; ++q)
                    a4[q] = fmaf(vs[p][base + q], fi, a4[q]);
            }
            *(float4*)&w1s[p][(a_*8 + j_)*12 + h_*4] =
                make_float4(a4[0], a4[1], a4[2], a4[3]);
        }
        // write prefetched row into the other vs buffer
        if (rr < 3 && t < 128) ((float4*)&vs[p ^ 1][0])[t] = vpf;

        lds_barrier();   // the ONLY barrier this row

        // ---- y stage: per s, compute w2v from w1s[p] (broadcast reads) ----
        {
            float4* y4 = (float4*)(y + (size_t)n * 4096);
            #pragma unroll
            for (int s = 0; s < 4; ++s) {
                const int A = s*4 + w_;      // wave-uniform
                float w2v[8] = {0.f,0.f,0.f,0.f,0.f,0.f,0.f,0.f};
                #pragma unroll
                for (int j = 0; j < 8; ++j) {
                    const int wb = (A*8 + j) * 12;
                    float4 wlo = *(const float4*)&w1s[p][wb];
                    float4 whi = *(const float4*)&w1s[p][wb + 4];
                    const float fj = fr1[j];
                    w2v[0] = fmaf(wlo.x, fj, w2v[0]);
                    w2v[1] = fmaf(wlo.y, fj, w2v[1]);
                    w2v[2] = fmaf(wlo.z, fj, w2v[2]);
                    w2v[3] = fmaf(wlo.w, fj, w2v[3]);
                    w2v[4] = fmaf(whi.x, fj, w2v[4]);
                    w2v[5] = fmaf(whi.y, fj, w2v[5]);
                    w2v[6] = fmaf(whi.z, fj, w2v[6]);
                    w2v[7] = fmaf(whi.w, fj, w2v[7]);
                }
                float4 bb = (s == 0) ? bb0 : (s == 1) ? bb1
                          : (s == 2) ? bb2 : bb3;
                float rv0 = bb.x, rv1 = bb.y, rv2 = bb.z, rv3 = bb.w;
                #pragma unroll
                for (int k = 0; k < 8; ++k) {
                    rv0 = fmaf(w2v[k], f2r[0*8 + k], rv0);
                    rv1 = fmaf(w2v[k], f2r[1*8 + k], rv1);
                    rv2 = fmaf(w2v[k], f2r[2*8 + k], rv2);
                    rv3 = fmaf(w2v[k], f2r[3*8 + k], rv3);
                }
                y4[s*256 + t] = make_float4(rv0, rv1, rv2, rv3);
            }
        }
        // no trailing barrier: w1s[p^1] (next row's target) is not being
        // read by anyone this row, and barrier(r+1) orders the rest.
    }
}

// ---------------------------------------------------------------------------
extern "C" void kernel_launch(void* const* d_in, const int* in_sizes, int n_in,
                              void* d_out, int out_size, void* d_ws, size_t ws_size,
                              hipStream_t stream)
{
    const float* x    = (const float*)d_in[0];
    const float* core = (const float*)d_in[1];
    const float* f0   = (const float*)d_in[2];
    const float* f1   = (const float*)d_in[3];
    const float* f2   = (const float*)d_in[4];
    const float* f3   = (const float*)d_in[5];
    const float* f4   = (const float*)d_in[6];
    const float* f5   = (const float*)d_in[7];
    const float* bias = (const float*)d_in[8];
    float* y = (float*)d_out;

    const int N = in_sizes[0] / 4096;

    // workspace: u3b bf16 [N,512] (4MB) | coreb bf16 [512,512] (0.5MB)
    //          | v fp32 [N,512] (8MB)
    unsigned short* u3b   = (unsigned short*)d_ws;
    unsigned short* coreb = u3b + (size_t)N * 512;
    float*          v     = (float*)(coreb + 512 * 512);

    k_in_contract<<<N, THREADS, 0, stream>>>(x, f3, f4, f5, u3b, N);
    k_convert_core<<<256, THREADS, 0, stream>>>(core, coreb);
    dim3 gb(N / 128, 512 / 32);
    k_core_gemm_mfma<<<gb, THREADS, 0, stream>>>(u3b, coreb, v, N);
    k_out_expand7<<<N / 4, THREADS, 0, stream>>>(v, f0, f1, f2, bias, y, N);
}

// Round 11
// 153.687 us; speedup vs baseline: 1.0160x; 1.0160x over previous
//
#include <hip/hip_runtime.h>

#define THREADS 256

typedef __attribute__((ext_vector_type(8))) short bf16x8;
typedef __attribute__((ext_vector_type(4))) float f32x4;

// fp32 -> bf16 with round-to-nearest-even (matches HW convert)
__device__ inline unsigned short f2bf(float f) {
    union { float f; unsigned int u; } v; v.f = f;
    unsigned int r = v.u + 0x7fffu + ((v.u >> 16) & 1u);
    return (unsigned short)(r >> 16);
}

// LDS-only barrier: orders LDS producer/consumer WITHOUT draining vmcnt —
// global loads/stores issued before it stay in flight (unlike __syncthreads).
__device__ inline void lds_barrier() {
    asm volatile("s_waitcnt lgkmcnt(0)" ::: "memory");
    __builtin_amdgcn_s_barrier();
    __builtin_amdgcn_sched_barrier(0);
}

// ---------------------------------------------------------------------------
// Kernel A (v8): in-side contraction, 4 ROWS PER BLOCK, pipelined.
//   x[N,4096] -> u3b[N,512] (bf16). Stage math bit-identical to the R0
//   kernel; restructured with the expand6 recipe (R9's proven win):
//   - T14 prefetch: next row's x (4 float4 regs) issued before u1 compute;
//     lds_barrier keeps it in flight across barriers (no vmcnt drain).
//   - u1s/u2s double-buffered (p = rr&1, full unroll -> static indices).
//   - 2 lds_barriers/row. Safety: row r touches only buffers [p]; the
//     earliest re-touch of [p] is row r+2, separated by >=3 barriers.
//   - f4/f3 per-thread rows hoisted out of the row loop (loop-invariant).
//   Grid N/4 = 1024 blocks; LDS ~29 KB; ~100 VGPR.
// ---------------------------------------------------------------------------
__global__ __launch_bounds__(THREADS) void k_in_contract8(
    const float* __restrict__ x,
    const float* __restrict__ f3, const float* __restrict__ f4,
    const float* __restrict__ f5,
    unsigned short* __restrict__ u3b, int N)
{
    const int t  = threadIdx.x;
    const int r0 = blockIdx.x * 4;

    __shared__ float fs[256];            // f3 [0..128) | f4 [128..256)
    __shared__ float u1s[2][256 * 9];    // [de][n6], pad 9
    __shared__ float u2s[2][128 * 9];    // [d*8+m][n6], pad 9

    if (t < 128) { fs[t] = f3[t]; fs[128 + t] = f4[t]; }

    // roles (fixed per thread, same decomposition as R0 kernel)
    const int d2 = t >> 4, m2 = (t >> 1) & 7, h2 = t & 1;   // u2 stage
    const int l3 = t >> 5, m3 = (t >> 2) & 7, h3 = t & 3;   // u3 stage

    // row 0 x chunk -> regs
    float4 xc0, xc1, xc2, xc3;
    {
        const float4* xr = (const float4*)(x + (size_t)r0 * 4096 + t * 16);
        xc0 = xr[0]; xc1 = xr[1]; xc2 = xr[2]; xc3 = xr[3];
    }

    lds_barrier();   // fs visible

    // hoisted factor rows (loop-invariant across the 4 rows)
    float fr4[16], fr3[16];
    #pragma unroll
    for (int e = 0; e < 16; ++e) fr4[e] = fs[128 + e*8 + m2];
    #pragma unroll
    for (int d = 0; d < 16; ++d) fr3[d] = fs[d*8 + l3];

    #pragma unroll
    for (int rr = 0; rr < 4; ++rr) {     // full unroll: p static
        const int n = r0 + rr;
        const int p = rr & 1;

        // T14: issue next row's x load before this row's compute
        float4 xn0, xn1, xn2, xn3;
        if (rr < 3) {
            const float4* xr = (const float4*)(x + (size_t)(n + 1) * 4096 + t * 16);
            xn0 = xr[0]; xn1 = xr[1]; xn2 = xr[2]; xn3 = xr[3];
        }

        // ---- u1 stage (lane-local): acc8[n6] = sum_f xv[f] f5[f,n6] ----
        {
            float xv[16] = {xc0.x,xc0.y,xc0.z,xc0.w, xc1.x,xc1.y,xc1.z,xc1.w,
                            xc2.x,xc2.y,xc2.z,xc2.w, xc3.x,xc3.y,xc3.z,xc3.w};
            float acc8[8];
            #pragma unroll
            for (int q = 0; q < 8; ++q) acc8[q] = 0.f;
            #pragma unroll
            for (int f = 0; f < 16; ++f) {
                const float xf = xv[f];
                #pragma unroll
                for (int n6 = 0; n6 < 8; ++n6)
                    acc8[n6] = fmaf(xf, f5[f*8 + n6], acc8[n6]);  // f5 uniform
            }
            #pragma unroll
            for (int n6 = 0; n6 < 8; ++n6) u1s[p][t*9 + n6] = acc8[n6];
        }
        lds_barrier();   // u1s[p] visible

        // ---- u2 stage: reads u1s[p], writes u2s[p] ----
        {
            float a4[4] = {0.f, 0.f, 0.f, 0.f};
            #pragma unroll
            for (int e = 0; e < 16; ++e) {
                const int base = (d2*16 + e)*9 + h2*4;
                const float fe = fr4[e];
                #pragma unroll
                for (int q = 0; q < 4; ++q)
                    a4[q] = fmaf(u1s[p][base + q], fe, a4[q]);
            }
            #pragma unroll
            for (int q = 0; q < 4; ++q)
                u2s[p][(d2*8 + m2)*9 + h2*4 + q] = a4[q];
        }
        lds_barrier();   // u2s[p] visible

        // ---- u3 stage: reads u2s[p], store u3b row (coalesced dword) ----
        {
            float a2[2] = {0.f, 0.f};
            #pragma unroll
            for (int d = 0; d < 16; ++d) {
                const int base = (d*8 + m3)*9 + h3*2;
                a2[0] = fmaf(u2s[p][base],     fr3[d], a2[0]);
                a2[1] = fmaf(u2s[p][base + 1], fr3[d], a2[1]);
            }
            unsigned int pk = (unsigned int)f2bf(a2[0]) |
                              ((unsigned int)f2bf(a2[1]) << 16);
            ((unsigned int*)u3b)[(size_t)n * 256 + t] = pk;  // stays in flight
        }
        // no trailing barrier: next row writes u1s[p^1] (untouched this row)

        if (rr < 3) { xc0 = xn0; xc1 = xn1; xc2 = xn2; xc3 = xn3; }
    }
}

// ---------------------------------------------------------------------------
// core fp32 [512,512] -> bf16. (FROZEN)
// ---------------------------------------------------------------------------
__global__ __launch_bounds__(THREADS) void k_convert_core(
    const float* __restrict__ core, unsigned short* __restrict__ coreb)
{
    const int i = blockIdx.x * THREADS + threadIdx.x;
    float4 c = ((const float4*)core)[i];
    ushort4 o;
    o.x = f2bf(c.x); o.y = f2bf(c.y); o.z = f2bf(c.z); o.w = f2bf(c.w);
    ((ushort4*)coreb)[i] = o;
}

// ---------------------------------------------------------------------------
// Kernel B: MFMA GEMM (EXACT round-0 proven version, ~8.6 us. FROZEN.)
//   Wave tile 32x32 (2x2 of 16x16x32 bf16). Grid (32,16) = 512 blocks.
// ---------------------------------------------------------------------------
__global__ __launch_bounds__(THREADS) void k_core_gemm_mfma(
    const unsigned short* __restrict__ u3b,
    const unsigned short* __restrict__ coreb,
    float* __restrict__ v, int N)
{
    const int t    = threadIdx.x;
    const int lane = t & 63;
    const int wave = t >> 6;
    const int m0 = blockIdx.x * 128 + wave * 32;
    const int p0 = blockIdx.y * 32;
    const int lr = lane & 15;
    const int lq = lane >> 4;

    const unsigned short* aptr0 = u3b   + (size_t)(m0 + lr) * 512 + lq * 8;
    const unsigned short* aptr1 = aptr0 + 16 * 512;
    const unsigned short* bptr0 = coreb + (size_t)(p0 + lr) * 512 + lq * 8;
    const unsigned short* bptr1 = bptr0 + 16 * 512;

    f32x4 acc00 = {0.f,0.f,0.f,0.f}, acc01 = {0.f,0.f,0.f,0.f};
    f32x4 acc10 = {0.f,0.f,0.f,0.f}, acc11 = {0.f,0.f,0.f,0.f};

    #pragma unroll
    for (int k0 = 0; k0 < 512; k0 += 32) {
        bf16x8 a0 = *(const bf16x8*)(aptr0 + k0);
        bf16x8 a1 = *(const bf16x8*)(aptr1 + k0);
        bf16x8 b0 = *(const bf16x8*)(bptr0 + k0);
        bf16x8 b1 = *(const bf16x8*)(bptr1 + k0);
        acc00 = __builtin_amdgcn_mfma_f32_16x16x32_bf16(a0, b0, acc00, 0, 0, 0);
        acc01 = __builtin_amdgcn_mfma_f32_16x16x32_bf16(a0, b1, acc01, 0, 0, 0);
        acc10 = __builtin_amdgcn_mfma_f32_16x16x32_bf16(a1, b0, acc10, 0, 0, 0);
        acc11 = __builtin_amdgcn_mfma_f32_16x16x32_bf16(a1, b1, acc11, 0, 0, 0);
    }

    const int row = m0 + lq * 4;
    const int col = p0 + lr;
    #pragma unroll
    for (int r = 0; r < 4; ++r) {
        v[(size_t)(row + r) * 512 + col]           = acc00[r];
        v[(size_t)(row + r) * 512 + col + 16]      = acc01[r];
        v[(size_t)(row + 16 + r) * 512 + col]      = acc10[r];
        v[(size_t)(row + 16 + r) * 512 + col + 16] = acc11[r];
    }
}

// ---------------------------------------------------------------------------
// Kernel C (v6): 4 rows/block, store-pipelined. (EXACT R9 proven version,
//   ~29.4 us — best measured expansion. expand7's barrier-thinning traded
//   LDS reuse for 4x redundant w2 FMAs and regressed; reverted. FROZEN.)
// ---------------------------------------------------------------------------
__global__ __launch_bounds__(THREADS) void k_out_expand6(
    const float* __restrict__ v,
    const float* __restrict__ f0, const float* __restrict__ f1,
    const float* __restrict__ f2, const float* __restrict__ bias,
    float* __restrict__ y, int N)
{
    const int t  = threadIdx.x;
    const int r0 = blockIdx.x * 4;

    __shared__ float fs[256];         // f0 [0..128) | f1 [128..256)
    __shared__ float vs[512];
    __shared__ float w1s[128 * 9];    // [a*8+j][k], pad 9
    __shared__ float w2s[8 * 257];    // [k][a*16+b], pad 257

    if (t < 128) { fs[t] = f0[t]; fs[128 + t] = f1[t]; }
    if (t < 128) ((float4*)vs)[t] = ((const float4*)(v + (size_t)r0 * 512))[t];

    float f2r[32];
    {
        const float4* fp = (const float4*)(f2 + ((t & 3) * 4) * 8);
        #pragma unroll
        for (int q8 = 0; q8 < 8; ++q8) {
            float4 ff = fp[q8];
            f2r[q8*4+0] = ff.x; f2r[q8*4+1] = ff.y;
            f2r[q8*4+2] = ff.z; f2r[q8*4+3] = ff.w;
        }
    }
    const float4* bias4 = (const float4*)bias;
    float4 bb0 = bias4[0*256 + t], bb1 = bias4[1*256 + t];
    float4 bb2 = bias4[2*256 + t], bb3 = bias4[3*256 + t];

    lds_barrier();   // fs + vs(row 0) visible

    const int a_ = t >> 4, j_ = (t >> 1) & 7, h_ = t & 1;   // w1 roles
    const int b_ = t & 15;                                   // w2 role
    const int w_ = t >> 6, B_ = (t >> 2) & 15;               // y roles

    float fr0[8], fr1[8];
    #pragma unroll
    for (int i = 0; i < 8; ++i) fr0[i] = fs[a_*8 + i];
    #pragma unroll
    for (int j = 0; j < 8; ++j) fr1[j] = fs[128 + b_*8 + j];

    #pragma unroll 1
    for (int rr = 0; rr < 4; ++rr) {
        const int n = r0 + rr;

        float4 vpf = make_float4(0.f, 0.f, 0.f, 0.f);
        if (rr < 3 && t < 128)
            vpf = ((const float4*)(v + (size_t)(n + 1) * 512))[t];

        // ---- w1 stage ----
        {
            float a4[4] = {0.f, 0.f, 0.f, 0.f};
            #pragma unroll
            for (int i = 0; i < 8; ++i) {
                const int base = i*64 + j_*8 + h_*4;
                const float fi = fr0[i];
                #pragma unroll
                for (int q = 0; q < 4; ++q)
                    a4[q] = fmaf(vs[base + q], fi, a4[q]);
            }
            #pragma unroll
            for (int q = 0; q < 4; ++q) w1s[(a_*8 + j_)*9 + h_*4 + q] = a4[q];
        }
        lds_barrier();

        // ---- w2 stage ----
        {
            float w2[8] = {0.f,0.f,0.f,0.f,0.f,0.f,0.f,0.f};
            #pragma unroll
            for (int j = 0; j < 8; ++j) {
                const int base = (a_*8 + j)*9;
                const float fj = fr1[j];
                #pragma unroll
                for (int k = 0; k < 8; ++k)
                    w2[k] = fmaf(w1s[base + k], fj, w2[k]);
            }
            #pragma unroll
            for (int k = 0; k < 8; ++k) w2s[k*257 + t] = w2[k];
        }
        if (rr < 3 && t < 128) ((float4*)vs)[t] = vpf;
        lds_barrier();

        // ---- y stage: coalesced 1KB/wave stores ----
        {
            float4* y4 = (float4*)(y + (size_t)n * 4096);
            #pragma unroll
            for (int s = 0; s < 4; ++s) {
                const int AB = (s*4 + w_) * 16 + B_;
                float w2v[8];
                #pragma unroll
                for (int k = 0; k < 8; ++k) w2v[k] = w2s[k*257 + AB];

                float4 bb = (s == 0) ? bb0 : (s == 1) ? bb1
                          : (s == 2) ? bb2 : bb3;
                float rv0 = bb.x, rv1 = bb.y, rv2 = bb.z, rv3 = bb.w;
                #pragma unroll
                for (int k = 0; k < 8; ++k) {
                    rv0 = fmaf(w2v[k], f2r[0*8 + k], rv0);
                    rv1 = fmaf(w2v[k], f2r[1*8 + k], rv1);
                    rv2 = fmaf(w2v[k], f2r[2*8 + k], rv2);
                    rv3 = fmaf(w2v[k], f2r[3*8 + k], rv3);
                }
                y4[s*256 + t] = make_float4(rv0, rv1, rv2, rv3);
            }
        }
        lds_barrier();
    }
}

// ---------------------------------------------------------------------------
extern "C" void kernel_launch(void* const* d_in, const int* in_sizes, int n_in,
                              void* d_out, int out_size, void* d_ws, size_t ws_size,
                              hipStream_t stream)
{
    const float* x    = (const float*)d_in[0];
    const float* core = (const float*)d_in[1];
    const float* f0   = (const float*)d_in[2];
    const float* f1   = (const float*)d_in[3];
    const float* f2   = (const float*)d_in[4];
    const float* f3   = (const float*)d_in[5];
    const float* f4   = (const float*)d_in[6];
    const float* f5   = (const float*)d_in[7];
    const float* bias = (const float*)d_in[8];
    float* y = (float*)d_out;

    const int N = in_sizes[0] / 4096;

    // workspace: u3b bf16 [N,512] (4MB) | coreb bf16 [512,512] (0.5MB)
    //          | v fp32 [N,512] (8MB)
    unsigned short* u3b   = (unsigned short*)d_ws;
    unsigned short* coreb = u3b + (size_t)N * 512;
    float*          v     = (float*)(coreb + 512 * 512);

    k_in_contract8<<<N / 4, THREADS, 0, stream>>>(x, f3, f4, f5, u3b, N);
    k_convert_core<<<256, THREADS, 0, stream>>>(core, coreb);
    dim3 gb(N / 128, 512 / 32);
    k_core_gemm_mfma<<<gb, THREADS, 0, stream>>>(u3b, coreb, v, N);
    k_out_expand6<<<N / 4, THREADS, 0, stream>>>(v, f0, f1, f2, bias, y, N);
}